// Round 1
// baseline (1134.265 us; speedup 1.0000x reference)
//
#include <hip/hip_runtime.h>
#include <math.h>

#define HDIM 2048
#define NTOK 4096
#define NHEAD 16
#define HEADD 128
#define TSEQ 2048
#define NBATCH 2

typedef float f32x4 __attribute__((ext_vector_type(4)));
typedef short bf16x8 __attribute__((ext_vector_type(8)));

__device__ __forceinline__ unsigned short f2bf(float f) {
  union { float f; unsigned u; } v; v.f = f;
  unsigned r = v.u + 0x7FFFu + ((v.u >> 16) & 1u);
  return (unsigned short)(r >> 16);
}

__device__ __forceinline__ float gelu_tanh_f(float x) {
  float z = 0.7978845608028654f * (x + 0.044715f * x * x * x);
  float e = __expf(2.f * z);
  float th = 1.f - 2.f / (e + 1.f);
  return 0.5f * x * (1.f + th);
}

#define GLL16(g, l) __builtin_amdgcn_global_load_lds( \
    (const __attribute__((address_space(1))) unsigned int*)(g), \
    (__attribute__((address_space(3))) unsigned int*)(l), 16, 0, 0)

// ---------------- LayerNorm: fp32 in, bf16 out. one block per token ----------------
__global__ __launch_bounds__(256) void ln_kernel(const float* __restrict__ in,
                                                 const float* __restrict__ scale,
                                                 const float* __restrict__ shift,
                                                 unsigned short* __restrict__ out) {
  int row = blockIdx.x;
  int t = threadIdx.x;
  const float4* r4 = (const float4*)(in + (size_t)row * HDIM);
  float4 v0 = r4[t];
  float4 v1 = r4[t + 256];
  float sum = v0.x + v0.y + v0.z + v0.w + v1.x + v1.y + v1.z + v1.w;
  float sq  = v0.x*v0.x + v0.y*v0.y + v0.z*v0.z + v0.w*v0.w +
              v1.x*v1.x + v1.y*v1.y + v1.z*v1.z + v1.w*v1.w;
  for (int o = 32; o > 0; o >>= 1) {
    sum += __shfl_down(sum, o);
    sq  += __shfl_down(sq, o);
  }
  __shared__ float red[8];
  __shared__ float stat[2];
  int lane = t & 63, w = t >> 6;
  if (lane == 0) { red[w] = sum; red[4 + w] = sq; }
  __syncthreads();
  if (t == 0) {
    float s = red[0] + red[1] + red[2] + red[3];
    float q = red[4] + red[5] + red[6] + red[7];
    float mean = s / HDIM;
    float var = q / HDIM - mean * mean;
    stat[0] = mean;
    stat[1] = rsqrtf(var + 1e-5f);
  }
  __syncthreads();
  float mean = stat[0], rstd = stat[1];
  const float4* sc4 = (const float4*)scale;
  const float4* sh4 = (const float4*)shift;
  float4 s0 = sc4[t], s1 = sc4[t + 256];
  float4 h0 = sh4[t], h1 = sh4[t + 256];
  ushort4 a, b;
  a.x = f2bf(s0.x * ((v0.x - mean) * rstd) + h0.x);
  a.y = f2bf(s0.y * ((v0.y - mean) * rstd) + h0.y);
  a.z = f2bf(s0.z * ((v0.z - mean) * rstd) + h0.z);
  a.w = f2bf(s0.w * ((v0.w - mean) * rstd) + h0.w);
  b.x = f2bf(s1.x * ((v1.x - mean) * rstd) + h1.x);
  b.y = f2bf(s1.y * ((v1.y - mean) * rstd) + h1.y);
  b.z = f2bf(s1.z * ((v1.z - mean) * rstd) + h1.z);
  b.w = f2bf(s1.w * ((v1.w - mean) * rstd) + h1.w);
  *(ushort4*)&out[(size_t)row * HDIM + t * 4] = a;
  *(ushort4*)&out[(size_t)row * HDIM + 1024 + t * 4] = b;
}

// ---------------- cast + transpose: W[K,N] fp32 -> Wt[N,K] bf16 ----------------
__global__ __launch_bounds__(256) void castT_kernel(const float* __restrict__ W,
                                                    unsigned short* __restrict__ Wt,
                                                    int K, int N) {
  __shared__ float T[64][65];
  int k0 = blockIdx.x * 64, n0 = blockIdx.y * 64;
  int c = threadIdx.x & 15, r = threadIdx.x >> 4;
#pragma unroll
  for (int p = 0; p < 4; p++) {
    int kr = r + p * 16;
    float4 v = *(const float4*)&W[(size_t)(k0 + kr) * N + n0 + c * 4];
    T[kr][c * 4 + 0] = v.x; T[kr][c * 4 + 1] = v.y;
    T[kr][c * 4 + 2] = v.z; T[kr][c * 4 + 3] = v.w;
  }
  __syncthreads();
#pragma unroll
  for (int p = 0; p < 4; p++) {
    int nr = r + p * 16;
    ushort4 o;
    o.x = f2bf(T[c * 4 + 0][nr]);
    o.y = f2bf(T[c * 4 + 1][nr]);
    o.z = f2bf(T[c * 4 + 2][nr]);
    o.w = f2bf(T[c * 4 + 3][nr]);
    *(ushort4*)&Wt[(size_t)(n0 + nr) * K + k0 + c * 4] = o;
  }
}

// ---------------- 8-phase 256-row MFMA GEMM: C[M,N] = A[M,K] @ Bt[N,K]^T -------------
// BM=256, BK=64, 512 threads = 8 waves (2M x 4N), per-wave 128 x (BN/4).
// LDS: double-buffered K-tiles, A 2x32KB + B 2x(BN*128B). BN=256 -> 128KB, BN=128 -> 96KB.
// Schedule (T3+T4+T5): per iteration, 2 K-tiles x 4 quadrant phases; each phase
//   {ds_read frag subtile | stage 1 half-tile via global_load_lds} -> raw s_barrier ->
//   lgkmcnt(0) -> setprio(1) 16|8 MFMA setprio(0) -> barrier.  vmcnt(6|5) only at
//   phases 4 and 8 (counted, never 0 mid-loop).
// Half-tiles defined by phase access: A-half qm = rows {qm*64..} of both wave-blocks,
//   B-half qn = qn-cols of each wave panel.  Stage order Ah0,Bh1,Ah1,Bh0 shifted so
//   each stage issues exactly one barrier after that region's last ds_read.
// LDS swizzle: linear dest (gload_lds requirement), inverse-swizzled global source,
//   ds_read chunk ^= row&7 (same involution; measured 0 bank conflicts on this family).
template<int BN>
__global__ __launch_bounds__(512, 2) void gemm256(const unsigned short* __restrict__ A,
                                                  const unsigned short* __restrict__ Bt,
                                                  float* __restrict__ Cf,
                                                  unsigned short* __restrict__ Cb,
                                                  const float* __restrict__ bias,
                                                  const float* __restrict__ resid,
                                                  int M, int N, int K, int act_gelu,
                                                  int qkv_mode,
                                                  unsigned short* __restrict__ Qo,
                                                  unsigned short* __restrict__ Ko,
                                                  unsigned short* __restrict__ Vto,
                                                  int rm, int rn, int xc) {
  constexpr int NIT = BN / 64;   // col frags per wave (4 or 2)
  constexpr int NB  = NIT / 2;   // col frags per quadrant (2 or 1)
  constexpr int BSZ = BN * 64;   // B tile elements per K-tile

  __shared__ unsigned short ldsA[2 * 16384];
  __shared__ unsigned short ldsB[2 * BSZ];

  const int tid = threadIdx.x;
  const int w = tid >> 6, lane = tid & 63;
  const int lm = lane & 15, qd = lane >> 4;
  const int wm = w >> 2, wn = w & 3;
  const int l8 = lane >> 3, l7 = lane & 7;

  // XCD-aware tile swizzle (bijective: grid % 8 == 0 for all call sites)
  int flat = blockIdx.y * gridDim.x + blockIdx.x;
  int xcd = flat & 7, l = flat >> 3;
  int tn_l = l % rn, tm_l = l / rn;
  int tm = (xcd / xc) * rm + tm_l;
  int tn = (xcd % xc) * rn + tn_l;
  int m0 = tm * 256, n0 = tn * BN;

  // ---- staging addressing (linear LDS dest, inverse-swizzled global src) ----
  const int swz = ((l7 ^ (l8 & 7)) << 3);            // source k-chunk (elements)
  const int arb = wm * 128 + (w & 3) * 16;           // A rowbase (qm=0, j=0)
  const unsigned short* pAs = A + (size_t)(m0 + arb + l8) * K + swz;
  unsigned short* lAs = ldsA + arb * 64;
  const int brb = (BN == 256) ? ((w >> 1) * 64 + (w & 1) * 16)
                              : ((w >> 1) * 32 + (w & 1) * 8);
  const unsigned short* pBs = Bt + (size_t)(n0 + brb + l8) * K + swz;
  unsigned short* lBs = ldsB + brb * 64;

  // ---- fragment read addressing: chunk = (ks*4+qd) ^ (row&7), row&7 == lane&7 ----
  const int ca0 = ((qd ^ l7) << 3);                  // ks=0 (ks=1: ca0 ^ 32)
  const unsigned short* pAr = ldsA + (wm * 128 + lm) * 64;
  const unsigned short* pBr = ldsB + (wn * (BN / 4) + lm) * 64;

  f32x4 acc[8][NIT] = {};
  bf16x8 a[2][4], b[2][NB];

#define STAGE_A(buf, qm, kt) do { \
    const unsigned short* _s = pAs + (size_t)(qm) * 64 * K + (size_t)(kt) * 64; \
    unsigned short* _d = lAs + (buf) * 16384 + (qm) * 4096; \
    GLL16(_s, _d); \
    GLL16(_s + (size_t)8 * K, _d + 512); \
  } while (0)

#define STAGE_B(buf, qn, kt) do { \
    if (BN == 256) { \
      const unsigned short* _s = pBs + (size_t)(qn) * 32 * K + (size_t)(kt) * 64; \
      unsigned short* _d = lBs + (buf) * BSZ + (qn) * 2048; \
      GLL16(_s, _d); \
      GLL16(_s + (size_t)8 * K, _d + 512); \
    } else { \
      const unsigned short* _s = pBs + (size_t)(qn) * 16 * K + (size_t)(kt) * 64; \
      unsigned short* _d = lBs + (buf) * BSZ + (qn) * 1024; \
      GLL16(_s, _d); \
    } \
  } while (0)

#define LDA(buf, qm) do { \
    _Pragma("unroll") \
    for (int mi = 0; mi < 4; mi++) { \
      a[0][mi] = *(const bf16x8*)(pAr + (buf) * 16384 + (qm) * 4096 + mi * 1024 + ca0); \
      a[1][mi] = *(const bf16x8*)(pAr + (buf) * 16384 + (qm) * 4096 + mi * 1024 + (ca0 ^ 32)); \
    } \
  } while (0)

#define LDB(buf, qn) do { \
    _Pragma("unroll") \
    for (int ni = 0; ni < NB; ni++) { \
      b[0][ni] = *(const bf16x8*)(pBr + (buf) * BSZ + (qn) * (NB * 1024) + ni * 1024 + ca0); \
      b[1][ni] = *(const bf16x8*)(pBr + (buf) * BSZ + (qn) * (NB * 1024) + ni * 1024 + (ca0 ^ 32)); \
    } \
  } while (0)

#define MFMA_PH(qm, qn) do { \
    __builtin_amdgcn_s_setprio(1); \
    _Pragma("unroll") \
    for (int ks = 0; ks < 2; ks++) \
      _Pragma("unroll") \
      for (int mi = 0; mi < 4; mi++) \
        _Pragma("unroll") \
        for (int ni = 0; ni < NB; ni++) \
          acc[(qm) * 4 + mi][(qn) * NB + ni] = __builtin_amdgcn_mfma_f32_16x16x32_bf16( \
              a[ks][mi], b[ks][ni], acc[(qm) * 4 + mi][(qn) * NB + ni], 0, 0, 0); \
    __builtin_amdgcn_s_setprio(0); \
  } while (0)

#define BARX() do { asm volatile("" ::: "memory"); __builtin_amdgcn_s_barrier(); \
                    asm volatile("" ::: "memory"); } while (0)
#define LGKM0() do { asm volatile("s_waitcnt lgkmcnt(0)" ::: "memory"); \
                     __builtin_amdgcn_sched_barrier(0); } while (0)
#define VM_SS() do { if (BN == 256) asm volatile("s_waitcnt vmcnt(6)" ::: "memory"); \
                     else           asm volatile("s_waitcnt vmcnt(5)" ::: "memory"); } while (0)
#define VM_0()  do { asm volatile("s_waitcnt vmcnt(0)" ::: "memory"); } while (0)

  const int niter = K >> 7;   // 2 K-tiles (BK=64) per iteration

  // prologue: tile0 all 4 halves; tile1 {Ah0,Bh1,Ah1} (Bh0 staged at phase 1)
  STAGE_A(0, 0, 0); STAGE_B(0, 1, 0); STAGE_A(0, 1, 0); STAGE_B(0, 0, 0);
  STAGE_A(1, 0, 1); STAGE_B(1, 1, 1); STAGE_A(1, 1, 1);
  VM_SS();
  BARX();

  for (int i = 0; i < niter; ++i) {
    const bool pf = (i + 1 < niter);
    const int te = 2 * i + 2, to = 2 * i + 3;
    // phase 1: even tile (buf0), quadrant (0,0)
    LDA(0, 0); LDB(0, 0);
    STAGE_B(1, 0, 2 * i + 1);
    BARX(); LGKM0();
    MFMA_PH(0, 0);
    BARX();
    // phase 2: (0,1)
    LDB(0, 1);
    if (pf) STAGE_A(0, 0, te);
    BARX(); LGKM0();
    MFMA_PH(0, 1);
    BARX();
    // phase 3: (1,1)
    LDA(0, 1);
    if (pf) STAGE_B(0, 1, te);
    BARX(); LGKM0();
    MFMA_PH(1, 1);
    BARX();
    // phase 4: (1,0) + counted vmcnt (next-odd tile fully landed)
    LDB(0, 0);
    if (pf) STAGE_A(0, 1, te);
    BARX(); LGKM0();
    MFMA_PH(1, 0);
    if (pf) VM_SS(); else VM_0();
    BARX();
    // phase 5: odd tile (buf1), (0,0)
    LDA(1, 0); LDB(1, 0);
    if (pf) STAGE_B(0, 0, te);
    BARX(); LGKM0();
    MFMA_PH(0, 0);
    BARX();
    // phase 6: (0,1)
    LDB(1, 1);
    if (pf) STAGE_A(1, 0, to);
    BARX(); LGKM0();
    MFMA_PH(0, 1);
    BARX();
    // phase 7: (1,1)
    LDA(1, 1);
    if (pf) STAGE_B(1, 1, to);
    BARX(); LGKM0();
    MFMA_PH(1, 1);
    BARX();
    // phase 8: (1,0) + counted vmcnt (next-even tile fully landed)
    LDB(1, 0);
    if (pf) STAGE_A(1, 1, to);
    BARX(); LGKM0();
    MFMA_PH(1, 0);
    if (pf) VM_SS();
    BARX();
  }

#undef STAGE_A
#undef STAGE_B
#undef LDA
#undef LDB
#undef MFMA_PH
#undef BARX
#undef LGKM0
#undef VM_SS
#undef VM_0

  if (qkv_mode) {
#pragma unroll
    for (int ni = 0; ni < NIT; ni++) {
      int n = n0 + wn * (BN / 4) + ni * 16 + lm;
      int region = n >> 11;  // 0=Q, 1=K, 2=V
      int h = (n & 2047) >> 7, d = n & 127;
#pragma unroll
      for (int mi = 0; mi < 8; mi++) {
        int mb = m0 + wm * 128 + mi * 16 + qd * 4;
        int bb = mb >> 11, t0 = mb & 2047;
        if (region == 2) {
          ushort4 u;
          u.x = f2bf(acc[mi][ni][0]); u.y = f2bf(acc[mi][ni][1]);
          u.z = f2bf(acc[mi][ni][2]); u.w = f2bf(acc[mi][ni][3]);
          *(ushort4*)&Vto[(((size_t)(bb * NHEAD + h)) * HEADD + d) * TSEQ + t0] = u;
        } else {
          unsigned short* dst = (region == 0) ? Qo : Ko;
          size_t base2 = (((size_t)(bb * NHEAD + h)) * TSEQ + t0) * HEADD + d;
#pragma unroll
          for (int r = 0; r < 4; r++)
            dst[base2 + (size_t)r * HEADD] = f2bf(acc[mi][ni][r]);
        }
      }
    }
    return;
  }

#pragma unroll
  for (int ni = 0; ni < NIT; ni++) {
    int n = n0 + wn * (BN / 4) + ni * 16 + lm;
    float bv = bias ? bias[n] : 0.f;
#pragma unroll
    for (int mi = 0; mi < 8; mi++) {
#pragma unroll
      for (int r = 0; r < 4; r++) {
        int m = m0 + wm * 128 + mi * 16 + qd * 4 + r;
        float v = acc[mi][ni][r] + bv;
        if (act_gelu) v = gelu_tanh_f(v);
        if (resid) v += resid[(size_t)m * N + n];
        if (Cb) Cb[(size_t)m * N + n] = f2bf(v);
        else Cf[(size_t)m * N + n] = v;
      }
    }
  }
}

// ---------------- MFMA flash attention: BQ=64, BK=64, D=128, bf16 in/out ----------------
__global__ __launch_bounds__(256, 4) void attn_mfma(const unsigned short* __restrict__ Qb,
                                                    const unsigned short* __restrict__ Kb,
                                                    const unsigned short* __restrict__ Vtb,
                                                    unsigned short* __restrict__ O) {
  __shared__ unsigned short ldsK[64 * 128];
  __shared__ unsigned short ldsV[128 * 64];
  __shared__ unsigned short ldsP[64 * 64];

  int tid = threadIdx.x;
  int w = tid >> 6, lane = tid & 63;
  int lm = lane & 15, qd = lane >> 4;
  int qt = blockIdx.x, hh = blockIdx.y, bb = blockIdx.z;
  int q0 = qt * 64;
  size_t hbase = (size_t)(bb * NHEAD + hh) * (size_t)(TSEQ * HEADD);
  const unsigned short* Qh = Qb + hbase;
  const unsigned short* Kh = Kb + hbase;
  const unsigned short* Vh = Vtb + hbase;

  bf16x8 qf[4];
  {
    const unsigned short* qp = Qh + (size_t)(q0 + w * 16 + lm) * HEADD + qd * 8;
#pragma unroll
    for (int kc = 0; kc < 4; kc++) qf[kc] = *(const bf16x8*)(qp + kc * 32);
  }

  int koff[4], voff[4], ldst[4];
#pragma unroll
  for (int it = 0; it < 4; it++) {
    int ci = it * 256 + w * 64 + lane;
    int key = ci >> 4, pos = ci & 15;
    koff[it] = key * HEADD + ((pos ^ (key & 15)) << 3);
    int d = ci >> 3, pv = ci & 7;
    voff[it] = d * TSEQ + ((pv ^ (d & 7)) << 3);
    ldst[it] = (it * 256 + w * 64) * 8;
  }

  f32x4 oacc[8] = {};
  float mrow[4], lrow[4];
#pragma unroll
  for (int r = 0; r < 4; r++) { mrow[r] = -3.0e38f; lrow[r] = 0.f; }
  const float scl = 0.08838834764831845f;

  for (int kt = 0; kt <= qt; kt++) {
    int k0 = kt * 64;
    __syncthreads();
#pragma unroll
    for (int it = 0; it < 4; it++) {
      GLL16(Kh + (size_t)k0 * HEADD + koff[it], ldsK + ldst[it]);
      GLL16(Vh + k0 + voff[it], ldsV + ldst[it]);
    }
    __syncthreads();

    f32x4 sacc[4] = {};
#pragma unroll
    for (int kb = 0; kb < 4; kb++) {
#pragma unroll
      for (int kc = 0; kc < 4; kc++) {
        bf16x8 kf = *(const bf16x8*)(ldsK + (kb * 16 + lm) * HEADD + (((kc * 4 + qd) ^ lm) << 3));
        sacc[kb] = __builtin_amdgcn_mfma_f32_16x16x32_bf16(qf[kc], kf, sacc[kb], 0, 0, 0);
      }
    }

    float sv[4][4];
    int qrow_g = q0 + w * 16 + qd * 4;
    bool diag = (kt == qt);
#pragma unroll
    for (int kb = 0; kb < 4; kb++) {
      int key_g = k0 + kb * 16 + lm;
#pragma unroll
      for (int r = 0; r < 4; r++) {
        float x = sacc[kb][r] * scl;
        sv[kb][r] = (diag && key_g > qrow_g + r) ? -3.0e38f : x;
      }
    }
    float mloc[4];
#pragma unroll
    for (int r = 0; r < 4; r++)
      mloc[r] = fmaxf(fmaxf(sv[0][r], sv[1][r]), fmaxf(sv[2][r], sv[3][r]));
#pragma unroll
    for (int dm = 1; dm < 16; dm <<= 1)
#pragma unroll
      for (int r = 0; r < 4; r++) mloc[r] = fmaxf(mloc[r], __shfl_xor(mloc[r], dm));
    float al[4], lloc[4];
#pragma unroll
    for (int r = 0; r < 4; r++) {
      float mnew = fmaxf(mrow[r], mloc[r]);
      al[r] = __expf(mrow[r] - mnew);
      mrow[r] = mnew;
      lloc[r] = 0.f;
    }
#pragma unroll
    for (int kb = 0; kb < 4; kb++) {
#pragma unroll
      for (int r = 0; r < 4; r++) {
        float p = __expf(sv[kb][r] - mrow[r]);
        lloc[r] += p;
        int row = w * 16 + qd * 4 + r;
        int chunk = (kb * 2 + (lm >> 3)) ^ (row & 7);
        ldsP[row * 64 + chunk * 8 + (lm & 7)] = f2bf(p);
      }
    }
#pragma unroll
    for (int dm = 1; dm < 16; dm <<= 1)
#pragma unroll
      for (int r = 0; r < 4; r++) lloc[r] += __shfl_xor(lloc[r], dm);
#pragma unroll
    for (int r = 0; r < 4; r++) lrow[r] = lrow[r] * al[r] + lloc[r];
#pragma unroll
    for (int dt = 0; dt < 8; dt++)
#pragma unroll
      for (int r = 0; r < 4; r++) oacc[dt][r] *= al[r];

    bf16x8 pf[2];
#pragma unroll
    for (int kc2 = 0; kc2 < 2; kc2++)
      pf[kc2] = *(const bf16x8*)(ldsP + (w * 16 + lm) * 64 + (((kc2 * 4 + qd) ^ (lm & 7)) << 3));
#pragma unroll
    for (int dt = 0; dt < 8; dt++) {
#pragma unroll
      for (int kc2 = 0; kc2 < 2; kc2++) {
        bf16x8 vf = *(const bf16x8*)(ldsV + (dt * 16 + lm) * 64 + (((kc2 * 4 + qd) ^ (lm & 7)) << 3));
        oacc[dt] = __builtin_amdgcn_mfma_f32_16x16x32_bf16(pf[kc2], vf, oacc[dt], 0, 0, 0);
      }
    }
  }

  float inv[4];
#pragma unroll
  for (int r = 0; r < 4; r++) inv[r] = 1.f / lrow[r];
#pragma unroll
  for (int dt = 0; dt < 8; dt++) {
#pragma unroll
    for (int r = 0; r < 4; r++) {
      int t = q0 + w * 16 + qd * 4 + r;
      size_t idx = ((size_t)(bb * TSEQ + t)) * HDIM + hh * HEADD + dt * 16 + lm;
      O[idx] = f2bf(oacc[dt][r] * inv[r]);
    }
  }
}

// ---------------- launch ----------------
extern "C" void kernel_launch(void* const* d_in, const int* in_sizes, int n_in,
                              void* d_out, int out_size, void* d_ws, size_t ws_size,
                              hipStream_t stream) {
  const float* x         = (const float*)d_in[0];
  const float* wq        = (const float*)d_in[1];
  const float* wk        = (const float*)d_in[2];
  const float* wv        = (const float*)d_in[3];
  const float* wo        = (const float*)d_in[4];
  const float* ln1_scale = (const float*)d_in[5];
  const float* ln1_shift = (const float*)d_in[6];
  const float* ln2_scale = (const float*)d_in[7];
  const float* ln2_shift = (const float*)d_in[8];
  const float* w1        = (const float*)d_in[9];
  const float* b1        = (const float*)d_in[10];
  const float* w2        = (const float*)d_in[11];
  const float* b2        = (const float*)d_in[12];

  char* ws = (char*)d_ws;
  const size_t MB = 1ull << 20;
  unsigned short* h1    = (unsigned short*)(ws);
  float*          x2    = (float*)(ws);
  unsigned short* Qb    = (unsigned short*)(ws + 32 * MB);
  unsigned short* Kb    = (unsigned short*)(ws + 48 * MB);
  unsigned short* Vtb   = (unsigned short*)(ws + 64 * MB);
  unsigned short* attnO = (unsigned short*)(ws + 80 * MB);
  unsigned short* woT   = (unsigned short*)(ws + 96 * MB);
  unsigned short* qkvT  = (unsigned short*)(ws + 104 * MB);
  unsigned short* a1    = (unsigned short*)(ws + 32 * MB);
  unsigned short* h2    = (unsigned short*)(ws + 96 * MB);
  unsigned short* w1T   = (unsigned short*)(ws + 128 * MB);
  unsigned short* w2T   = (unsigned short*)(ws + 160 * MB);

  dim3 blk(256), blk5(512);
  ln_kernel<<<NTOK, blk, 0, stream>>>(x, ln1_scale, ln1_shift, h1);
  castT_kernel<<<dim3(32, 32), blk, 0, stream>>>(wq, qkvT, 2048, 2048);
  castT_kernel<<<dim3(32, 32), blk, 0, stream>>>(wk, qkvT + (size_t)2048 * 2048, 2048, 2048);
  castT_kernel<<<dim3(32, 32), blk, 0, stream>>>(wv, qkvT + (size_t)4096 * 2048, 2048, 2048);
  castT_kernel<<<dim3(32, 32), blk, 0, stream>>>(wo, woT, 2048, 2048);
  castT_kernel<<<dim3(32, 128), blk, 0, stream>>>(w1, w1T, 2048, 8192);
  castT_kernel<<<dim3(128, 32), blk, 0, stream>>>(w2, w2T, 8192, 2048);
  // QKV: BN=128, grid 48x16 = 768 blocks (3 exact CU-waves); xr=2,xc=4 -> rm=8, rn=12
  gemm256<128><<<dim3(48, 16), blk5, 0, stream>>>(
      h1, qkvT, nullptr, nullptr, nullptr, nullptr, 4096, 6144, 2048, 0, 1, Qb, Kb, Vtb,
      8, 12, 4);
  attn_mfma<<<dim3(TSEQ / 64, NHEAD, NBATCH), blk, 0, stream>>>(Qb, Kb, Vtb, attnO);
  // proj: BN=128, grid 16x16 = 256 blocks (1 exact wave); xr=4,xc=2 -> rm=4, rn=8
  gemm256<128><<<dim3(16, 16), blk5, 0, stream>>>(
      attnO, woT, x2, nullptr, nullptr, x, 4096, 2048, 2048, 0, 0, nullptr, nullptr, nullptr,
      4, 8, 2);
  ln_kernel<<<NTOK, blk, 0, stream>>>(x2, ln2_scale, ln2_shift, h2);
  // FFN1: BN=256, grid 32x16 = 512 blocks (2 exact waves); xr=2,xc=4 -> rm=8, rn=8
  gemm256<256><<<dim3(32, 16), blk5, 0, stream>>>(
      h2, w1T, nullptr, a1, b1, nullptr, 4096, 8192, 2048, 1, 0, nullptr, nullptr, nullptr,
      8, 8, 4);
  // FFN2: BN=128, grid 16x16 = 256 blocks; xr=4,xc=2 -> rm=4, rn=8
  gemm256<128><<<dim3(16, 16), blk5, 0, stream>>>(
      a1, w2T, (float*)d_out, nullptr, b2, x2, 4096, 2048, 8192, 0, 0, nullptr, nullptr, nullptr,
      4, 8, 2);
}

// Round 2
// 1083.732 us; speedup vs baseline: 1.0466x; 1.0466x over previous
//
#include <hip/hip_runtime.h>
#include <math.h>

#define HDIM 2048
#define NTOK 4096
#define NHEAD 16
#define HEADD 128
#define TSEQ 2048
#define NBATCH 2

typedef float f32x4 __attribute__((ext_vector_type(4)));
typedef short bf16x8 __attribute__((ext_vector_type(8)));

__device__ __forceinline__ unsigned short f2bf(float f) {
  union { float f; unsigned u; } v; v.f = f;
  unsigned r = v.u + 0x7FFFu + ((v.u >> 16) & 1u);
  return (unsigned short)(r >> 16);
}

__device__ __forceinline__ float gelu_tanh_f(float x) {
  float z = 0.7978845608028654f * (x + 0.044715f * x * x * x);
  float e = __expf(2.f * z);
  float th = 1.f - 2.f / (e + 1.f);
  return 0.5f * x * (1.f + th);
}

#define GLL16(g, l) __builtin_amdgcn_global_load_lds( \
    (const __attribute__((address_space(1))) unsigned int*)(g), \
    (__attribute__((address_space(3))) unsigned int*)(l), 16, 0, 0)

// ---------------- LayerNorm: fp32 in, bf16 out. one block per token ----------------
__global__ __launch_bounds__(256) void ln_kernel(const float* __restrict__ in,
                                                 const float* __restrict__ scale,
                                                 const float* __restrict__ shift,
                                                 unsigned short* __restrict__ out) {
  int row = blockIdx.x;
  int t = threadIdx.x;
  const float4* r4 = (const float4*)(in + (size_t)row * HDIM);
  float4 v0 = r4[t];
  float4 v1 = r4[t + 256];
  float sum = v0.x + v0.y + v0.z + v0.w + v1.x + v1.y + v1.z + v1.w;
  float sq  = v0.x*v0.x + v0.y*v0.y + v0.z*v0.z + v0.w*v0.w +
              v1.x*v1.x + v1.y*v1.y + v1.z*v1.z + v1.w*v1.w;
  for (int o = 32; o > 0; o >>= 1) {
    sum += __shfl_down(sum, o);
    sq  += __shfl_down(sq, o);
  }
  __shared__ float red[8];
  __shared__ float stat[2];
  int lane = t & 63, w = t >> 6;
  if (lane == 0) { red[w] = sum; red[4 + w] = sq; }
  __syncthreads();
  if (t == 0) {
    float s = red[0] + red[1] + red[2] + red[3];
    float q = red[4] + red[5] + red[6] + red[7];
    float mean = s / HDIM;
    float var = q / HDIM - mean * mean;
    stat[0] = mean;
    stat[1] = rsqrtf(var + 1e-5f);
  }
  __syncthreads();
  float mean = stat[0], rstd = stat[1];
  const float4* sc4 = (const float4*)scale;
  const float4* sh4 = (const float4*)shift;
  float4 s0 = sc4[t], s1 = sc4[t + 256];
  float4 h0 = sh4[t], h1 = sh4[t + 256];
  ushort4 a, b;
  a.x = f2bf(s0.x * ((v0.x - mean) * rstd) + h0.x);
  a.y = f2bf(s0.y * ((v0.y - mean) * rstd) + h0.y);
  a.z = f2bf(s0.z * ((v0.z - mean) * rstd) + h0.z);
  a.w = f2bf(s0.w * ((v0.w - mean) * rstd) + h0.w);
  b.x = f2bf(s1.x * ((v1.x - mean) * rstd) + h1.x);
  b.y = f2bf(s1.y * ((v1.y - mean) * rstd) + h1.y);
  b.z = f2bf(s1.z * ((v1.z - mean) * rstd) + h1.z);
  b.w = f2bf(s1.w * ((v1.w - mean) * rstd) + h1.w);
  *(ushort4*)&out[(size_t)row * HDIM + t * 4] = a;
  *(ushort4*)&out[(size_t)row * HDIM + 1024 + t * 4] = b;
}

// ---------------- cast + transpose: W[K,N] fp32 -> Wt[N,K] bf16 ----------------
__global__ __launch_bounds__(256) void castT_kernel(const float* __restrict__ W,
                                                    unsigned short* __restrict__ Wt,
                                                    int K, int N) {
  __shared__ float T[64][65];
  int k0 = blockIdx.x * 64, n0 = blockIdx.y * 64;
  int c = threadIdx.x & 15, r = threadIdx.x >> 4;
#pragma unroll
  for (int p = 0; p < 4; p++) {
    int kr = r + p * 16;
    float4 v = *(const float4*)&W[(size_t)(k0 + kr) * N + n0 + c * 4];
    T[kr][c * 4 + 0] = v.x; T[kr][c * 4 + 1] = v.y;
    T[kr][c * 4 + 2] = v.z; T[kr][c * 4 + 3] = v.w;
  }
  __syncthreads();
#pragma unroll
  for (int p = 0; p < 4; p++) {
    int nr = r + p * 16;
    ushort4 o;
    o.x = f2bf(T[c * 4 + 0][nr]);
    o.y = f2bf(T[c * 4 + 1][nr]);
    o.z = f2bf(T[c * 4 + 2][nr]);
    o.w = f2bf(T[c * 4 + 3][nr]);
    *(ushort4*)&Wt[(size_t)(n0 + nr) * K + k0 + c * 4] = o;
  }
}

// ---------------- 8-phase 256-row MFMA GEMM: C[M,N] = A[M,K] @ Bt[N,K]^T -------------
// BM=256, BK=64, 512 threads = 8 waves (2M x 4N), per-wave 128 x (BN/4).
// LDS: double-buffered K-tiles, A 2x32KB + B 2x(BN*128B). BN=256 -> 128KB, BN=128 -> 96KB.
// Schedule (T3+T4+T5): per iteration, 2 K-tiles x 4 quadrant phases; each phase
//   {ds_read frag subtile | stage 1 half-tile via global_load_lds} -> s_barrier ->
//   lgkmcnt(0) -> setprio(1) 16|8 MFMA setprio(0) -> barrier.  vmcnt(6|5) only at
//   phases 4 and 8 (counted, never 0 mid-loop).
// FENCES (round-2 fix): NO "memory" clobbers anywhere in the loop asm — a memory
//   clobber makes SIInsertWaitcnts drain vmcnt(0)+lgkmcnt(0) at every fence,
//   silently replacing the counted-vmcnt pipeline with a drain-per-phase loop
//   (round-1: MfmaUtil 22%, ~1000 idle cy/phase).  Ordering is instead pinned with
//   __builtin_amdgcn_sched_barrier(0), which has no memory semantics.
//   The manual counted vmcnt ledger is load-bearing: the toolchain does not order
//   plain ds_reads against LDS-DMA on its own.
template<int BN>
__global__ __launch_bounds__(512, 2) void gemm256(const unsigned short* __restrict__ A,
                                                  const unsigned short* __restrict__ Bt,
                                                  float* __restrict__ Cf,
                                                  unsigned short* __restrict__ Cb,
                                                  const float* __restrict__ bias,
                                                  const float* __restrict__ resid,
                                                  int M, int N, int K, int act_gelu,
                                                  int qkv_mode,
                                                  unsigned short* __restrict__ Qo,
                                                  unsigned short* __restrict__ Ko,
                                                  unsigned short* __restrict__ Vto,
                                                  int rm, int rn, int xc) {
  constexpr int NIT = BN / 64;   // col frags per wave (4 or 2)
  constexpr int NB  = NIT / 2;   // col frags per quadrant (2 or 1)
  constexpr int BSZ = BN * 64;   // B tile elements per K-tile

  __shared__ unsigned short ldsA[2 * 16384];
  __shared__ unsigned short ldsB[2 * BSZ];

  const int tid = threadIdx.x;
  const int w = tid >> 6, lane = tid & 63;
  const int lm = lane & 15, qd = lane >> 4;
  const int wm = w >> 2, wn = w & 3;
  const int l8 = lane >> 3, l7 = lane & 7;

  // XCD-aware tile swizzle (bijective: grid % 8 == 0 for all call sites)
  int flat = blockIdx.y * gridDim.x + blockIdx.x;
  int xcd = flat & 7, l = flat >> 3;
  int tn_l = l % rn, tm_l = l / rn;
  int tm = (xcd / xc) * rm + tm_l;
  int tn = (xcd % xc) * rn + tn_l;
  int m0 = tm * 256, n0 = tn * BN;

  // ---- staging addressing (linear LDS dest, inverse-swizzled global src) ----
  const int swz = ((l7 ^ (l8 & 7)) << 3);            // source k-chunk (elements)
  const int arb = wm * 128 + (w & 3) * 16;           // A rowbase (qm=0, j=0)
  const unsigned short* pAs = A + (size_t)(m0 + arb + l8) * K + swz;
  unsigned short* lAs = ldsA + arb * 64;
  const int brb = (BN == 256) ? ((w >> 1) * 64 + (w & 1) * 16)
                              : ((w >> 1) * 32 + (w & 1) * 8);
  const unsigned short* pBs = Bt + (size_t)(n0 + brb + l8) * K + swz;
  unsigned short* lBs = ldsB + brb * 64;

  // ---- fragment read addressing: chunk = (ks*4+qd) ^ (row&7), row&7 == lane&7 ----
  const int ca0 = ((qd ^ l7) << 3);                  // ks=0 (ks=1: ca0 ^ 32)
  const unsigned short* pAr = ldsA + (wm * 128 + lm) * 64;
  const unsigned short* pBr = ldsB + (wn * (BN / 4) + lm) * 64;

  f32x4 acc[8][NIT] = {};
  bf16x8 a[2][4], b[2][NB];

#define STAGE_A(buf, qm, kt) do { \
    const unsigned short* _s = pAs + (size_t)(qm) * 64 * K + (size_t)(kt) * 64; \
    unsigned short* _d = lAs + (buf) * 16384 + (qm) * 4096; \
    GLL16(_s, _d); \
    GLL16(_s + (size_t)8 * K, _d + 512); \
  } while (0)

#define STAGE_B(buf, qn, kt) do { \
    if (BN == 256) { \
      const unsigned short* _s = pBs + (size_t)(qn) * 32 * K + (size_t)(kt) * 64; \
      unsigned short* _d = lBs + (buf) * BSZ + (qn) * 2048; \
      GLL16(_s, _d); \
      GLL16(_s + (size_t)8 * K, _d + 512); \
    } else { \
      const unsigned short* _s = pBs + (size_t)(qn) * 16 * K + (size_t)(kt) * 64; \
      unsigned short* _d = lBs + (buf) * BSZ + (qn) * 1024; \
      GLL16(_s, _d); \
    } \
  } while (0)

#define LDA(buf, qm) do { \
    _Pragma("unroll") \
    for (int mi = 0; mi < 4; mi++) { \
      a[0][mi] = *(const bf16x8*)(pAr + (buf) * 16384 + (qm) * 4096 + mi * 1024 + ca0); \
      a[1][mi] = *(const bf16x8*)(pAr + (buf) * 16384 + (qm) * 4096 + mi * 1024 + (ca0 ^ 32)); \
    } \
  } while (0)

#define LDB(buf, qn) do { \
    _Pragma("unroll") \
    for (int ni = 0; ni < NB; ni++) { \
      b[0][ni] = *(const bf16x8*)(pBr + (buf) * BSZ + (qn) * (NB * 1024) + ni * 1024 + ca0); \
      b[1][ni] = *(const bf16x8*)(pBr + (buf) * BSZ + (qn) * (NB * 1024) + ni * 1024 + (ca0 ^ 32)); \
    } \
  } while (0)

#define MFMA_PH(qm, qn) do { \
    __builtin_amdgcn_s_setprio(1); \
    _Pragma("unroll") \
    for (int ks = 0; ks < 2; ks++) \
      _Pragma("unroll") \
      for (int mi = 0; mi < 4; mi++) \
        _Pragma("unroll") \
        for (int ni = 0; ni < NB; ni++) \
          acc[(qm) * 4 + mi][(qn) * NB + ni] = __builtin_amdgcn_mfma_f32_16x16x32_bf16( \
              a[ks][mi], b[ks][ni], acc[(qm) * 4 + mi][(qn) * NB + ni], 0, 0, 0); \
    __builtin_amdgcn_s_setprio(0); \
  } while (0)

// Fences: NO memory clobbers (see header comment).  sched_barrier(0) pins order.
#define BARX() do { __builtin_amdgcn_sched_barrier(0); __builtin_amdgcn_s_barrier(); \
                    __builtin_amdgcn_sched_barrier(0); } while (0)
#define LGKM0() do { asm volatile("s_waitcnt lgkmcnt(0)"); \
                     __builtin_amdgcn_sched_barrier(0); } while (0)
#define VM_SS() do { if (BN == 256) asm volatile("s_waitcnt vmcnt(6)"); \
                     else           asm volatile("s_waitcnt vmcnt(5)"); \
                     __builtin_amdgcn_sched_barrier(0); } while (0)
#define VM_0()  do { asm volatile("s_waitcnt vmcnt(0)"); \
                     __builtin_amdgcn_sched_barrier(0); } while (0)

  const int niter = K >> 7;   // 2 K-tiles (BK=64) per iteration

  // prologue: tile0 all 4 halves; tile1 {Ah0,Bh1,Ah1} (Bh0 staged at phase 1)
  STAGE_A(0, 0, 0); STAGE_B(0, 1, 0); STAGE_A(0, 1, 0); STAGE_B(0, 0, 0);
  STAGE_A(1, 0, 1); STAGE_B(1, 1, 1); STAGE_A(1, 1, 1);
  VM_SS();
  BARX();

  for (int i = 0; i < niter; ++i) {
    const bool pf = (i + 1 < niter);
    const int te = 2 * i + 2, to = 2 * i + 3;
    // phase 1: even tile (buf0), quadrant (0,0)
    LDA(0, 0); LDB(0, 0);
    STAGE_B(1, 0, 2 * i + 1);
    BARX(); LGKM0();
    MFMA_PH(0, 0);
    BARX();
    // phase 2: (0,1)
    LDB(0, 1);
    if (pf) STAGE_A(0, 0, te);
    BARX(); LGKM0();
    MFMA_PH(0, 1);
    BARX();
    // phase 3: (1,1)
    LDA(0, 1);
    if (pf) STAGE_B(0, 1, te);
    BARX(); LGKM0();
    MFMA_PH(1, 1);
    BARX();
    // phase 4: (1,0) + counted vmcnt (next-odd tile fully landed)
    LDB(0, 0);
    if (pf) STAGE_A(0, 1, te);
    BARX(); LGKM0();
    MFMA_PH(1, 0);
    if (pf) VM_SS(); else VM_0();
    BARX();
    // phase 5: odd tile (buf1), (0,0)
    LDA(1, 0); LDB(1, 0);
    if (pf) STAGE_B(0, 0, te);
    BARX(); LGKM0();
    MFMA_PH(0, 0);
    BARX();
    // phase 6: (0,1)
    LDB(1, 1);
    if (pf) STAGE_A(1, 0, to);
    BARX(); LGKM0();
    MFMA_PH(0, 1);
    BARX();
    // phase 7: (1,1)
    LDA(1, 1);
    if (pf) STAGE_B(1, 1, to);
    BARX(); LGKM0();
    MFMA_PH(1, 1);
    BARX();
    // phase 8: (1,0) + counted vmcnt (next-even tile fully landed)
    LDB(1, 0);
    if (pf) STAGE_A(1, 1, to);
    BARX(); LGKM0();
    MFMA_PH(1, 0);
    if (pf) VM_SS();
    BARX();
  }

#undef STAGE_A
#undef STAGE_B
#undef LDA
#undef LDB
#undef MFMA_PH
#undef BARX
#undef LGKM0
#undef VM_SS
#undef VM_0

  if (qkv_mode) {
#pragma unroll
    for (int ni = 0; ni < NIT; ni++) {
      int n = n0 + wn * (BN / 4) + ni * 16 + lm;
      int region = n >> 11;  // 0=Q, 1=K, 2=V
      int h = (n & 2047) >> 7, d = n & 127;
#pragma unroll
      for (int mi = 0; mi < 8; mi++) {
        int mb = m0 + wm * 128 + mi * 16 + qd * 4;
        int bb = mb >> 11, t0 = mb & 2047;
        if (region == 2) {
          ushort4 u;
          u.x = f2bf(acc[mi][ni][0]); u.y = f2bf(acc[mi][ni][1]);
          u.z = f2bf(acc[mi][ni][2]); u.w = f2bf(acc[mi][ni][3]);
          *(ushort4*)&Vto[(((size_t)(bb * NHEAD + h)) * HEADD + d) * TSEQ + t0] = u;
        } else {
          unsigned short* dst = (region == 0) ? Qo : Ko;
          size_t base2 = (((size_t)(bb * NHEAD + h)) * TSEQ + t0) * HEADD + d;
#pragma unroll
          for (int r = 0; r < 4; r++)
            dst[base2 + (size_t)r * HEADD] = f2bf(acc[mi][ni][r]);
        }
      }
    }
    return;
  }

#pragma unroll
  for (int ni = 0; ni < NIT; ni++) {
    int n = n0 + wn * (BN / 4) + ni * 16 + lm;
    float bv = bias ? bias[n] : 0.f;
#pragma unroll
    for (int mi = 0; mi < 8; mi++) {
#pragma unroll
      for (int r = 0; r < 4; r++) {
        int m = m0 + wm * 128 + mi * 16 + qd * 4 + r;
        float v = acc[mi][ni][r] + bv;
        if (act_gelu) v = gelu_tanh_f(v);
        if (resid) v += resid[(size_t)m * N + n];
        if (Cb) Cb[(size_t)m * N + n] = f2bf(v);
        else Cf[(size_t)m * N + n] = v;
      }
    }
  }
}

// ---------------- MFMA flash attention: BQ=64, BK=64, D=128, bf16 in/out ----------------
__global__ __launch_bounds__(256, 4) void attn_mfma(const unsigned short* __restrict__ Qb,
                                                    const unsigned short* __restrict__ Kb,
                                                    const unsigned short* __restrict__ Vtb,
                                                    unsigned short* __restrict__ O) {
  __shared__ unsigned short ldsK[64 * 128];
  __shared__ unsigned short ldsV[128 * 64];
  __shared__ unsigned short ldsP[64 * 64];

  int tid = threadIdx.x;
  int w = tid >> 6, lane = tid & 63;
  int lm = lane & 15, qd = lane >> 4;
  int qt = blockIdx.x, hh = blockIdx.y, bb = blockIdx.z;
  int q0 = qt * 64;
  size_t hbase = (size_t)(bb * NHEAD + hh) * (size_t)(TSEQ * HEADD);
  const unsigned short* Qh = Qb + hbase;
  const unsigned short* Kh = Kb + hbase;
  const unsigned short* Vh = Vtb + hbase;

  bf16x8 qf[4];
  {
    const unsigned short* qp = Qh + (size_t)(q0 + w * 16 + lm) * HEADD + qd * 8;
#pragma unroll
    for (int kc = 0; kc < 4; kc++) qf[kc] = *(const bf16x8*)(qp + kc * 32);
  }

  int koff[4], voff[4], ldst[4];
#pragma unroll
  for (int it = 0; it < 4; it++) {
    int ci = it * 256 + w * 64 + lane;
    int key = ci >> 4, pos = ci & 15;
    koff[it] = key * HEADD + ((pos ^ (key & 15)) << 3);
    int d = ci >> 3, pv = ci & 7;
    voff[it] = d * TSEQ + ((pv ^ (d & 7)) << 3);
    ldst[it] = (it * 256 + w * 64) * 8;
  }

  f32x4 oacc[8] = {};
  float mrow[4], lrow[4];
#pragma unroll
  for (int r = 0; r < 4; r++) { mrow[r] = -3.0e38f; lrow[r] = 0.f; }
  const float scl = 0.08838834764831845f;

  for (int kt = 0; kt <= qt; kt++) {
    int k0 = kt * 64;
    __syncthreads();
#pragma unroll
    for (int it = 0; it < 4; it++) {
      GLL16(Kh + (size_t)k0 * HEADD + koff[it], ldsK + ldst[it]);
      GLL16(Vh + k0 + voff[it], ldsV + ldst[it]);
    }
    __syncthreads();

    f32x4 sacc[4] = {};
#pragma unroll
    for (int kb = 0; kb < 4; kb++) {
#pragma unroll
      for (int kc = 0; kc < 4; kc++) {
        bf16x8 kf = *(const bf16x8*)(ldsK + (kb * 16 + lm) * HEADD + (((kc * 4 + qd) ^ lm) << 3));
        sacc[kb] = __builtin_amdgcn_mfma_f32_16x16x32_bf16(qf[kc], kf, sacc[kb], 0, 0, 0);
      }
    }

    float sv[4][4];
    int qrow_g = q0 + w * 16 + qd * 4;
    bool diag = (kt == qt);
#pragma unroll
    for (int kb = 0; kb < 4; kb++) {
      int key_g = k0 + kb * 16 + lm;
#pragma unroll
      for (int r = 0; r < 4; r++) {
        float x = sacc[kb][r] * scl;
        sv[kb][r] = (diag && key_g > qrow_g + r) ? -3.0e38f : x;
      }
    }
    float mloc[4];
#pragma unroll
    for (int r = 0; r < 4; r++)
      mloc[r] = fmaxf(fmaxf(sv[0][r], sv[1][r]), fmaxf(sv[2][r], sv[3][r]));
#pragma unroll
    for (int dm = 1; dm < 16; dm <<= 1)
#pragma unroll
      for (int r = 0; r < 4; r++) mloc[r] = fmaxf(mloc[r], __shfl_xor(mloc[r], dm));
    float al[4], lloc[4];
#pragma unroll
    for (int r = 0; r < 4; r++) {
      float mnew = fmaxf(mrow[r], mloc[r]);
      al[r] = __expf(mrow[r] - mnew);
      mrow[r] = mnew;
      lloc[r] = 0.f;
    }
#pragma unroll
    for (int kb = 0; kb < 4; kb++) {
#pragma unroll
      for (int r = 0; r < 4; r++) {
        float p = __expf(sv[kb][r] - mrow[r]);
        lloc[r] += p;
        int row = w * 16 + qd * 4 + r;
        int chunk = (kb * 2 + (lm >> 3)) ^ (row & 7);
        ldsP[row * 64 + chunk * 8 + (lm & 7)] = f2bf(p);
      }
    }
#pragma unroll
    for (int dm = 1; dm < 16; dm <<= 1)
#pragma unroll
      for (int r = 0; r < 4; r++) lloc[r] += __shfl_xor(lloc[r], dm);
#pragma unroll
    for (int r = 0; r < 4; r++) lrow[r] = lrow[r] * al[r] + lloc[r];
#pragma unroll
    for (int dt = 0; dt < 8; dt++)
#pragma unroll
      for (int r = 0; r < 4; r++) oacc[dt][r] *= al[r];

    bf16x8 pf[2];
#pragma unroll
    for (int kc2 = 0; kc2 < 2; kc2++)
      pf[kc2] = *(const bf16x8*)(ldsP + (w * 16 + lm) * 64 + (((kc2 * 4 + qd) ^ (lm & 7)) << 3));
#pragma unroll
    for (int dt = 0; dt < 8; dt++) {
#pragma unroll
      for (int kc2 = 0; kc2 < 2; kc2++) {
        bf16x8 vf = *(const bf16x8*)(ldsV + (dt * 16 + lm) * 64 + (((kc2 * 4 + qd) ^ (lm & 7)) << 3));
        oacc[dt] = __builtin_amdgcn_mfma_f32_16x16x32_bf16(pf[kc2], vf, oacc[dt], 0, 0, 0);
      }
    }
  }

  float inv[4];
#pragma unroll
  for (int r = 0; r < 4; r++) inv[r] = 1.f / lrow[r];
#pragma unroll
  for (int dt = 0; dt < 8; dt++) {
#pragma unroll
    for (int r = 0; r < 4; r++) {
      int t = q0 + w * 16 + qd * 4 + r;
      size_t idx = ((size_t)(bb * TSEQ + t)) * HDIM + hh * HEADD + dt * 16 + lm;
      O[idx] = f2bf(oacc[dt][r] * inv[r]);
    }
  }
}

// ---------------- launch ----------------
extern "C" void kernel_launch(void* const* d_in, const int* in_sizes, int n_in,
                              void* d_out, int out_size, void* d_ws, size_t ws_size,
                              hipStream_t stream) {
  const float* x         = (const float*)d_in[0];
  const float* wq        = (const float*)d_in[1];
  const float* wk        = (const float*)d_in[2];
  const float* wv        = (const float*)d_in[3];
  const float* wo        = (const float*)d_in[4];
  const float* ln1_scale = (const float*)d_in[5];
  const float* ln1_shift = (const float*)d_in[6];
  const float* ln2_scale = (const float*)d_in[7];
  const float* ln2_shift = (const float*)d_in[8];
  const float* w1        = (const float*)d_in[9];
  const float* b1        = (const float*)d_in[10];
  const float* w2        = (const float*)d_in[11];
  const float* b2        = (const float*)d_in[12];

  char* ws = (char*)d_ws;
  const size_t MB = 1ull << 20;
  unsigned short* h1    = (unsigned short*)(ws);
  float*          x2    = (float*)(ws);
  unsigned short* Qb    = (unsigned short*)(ws + 32 * MB);
  unsigned short* Kb    = (unsigned short*)(ws + 48 * MB);
  unsigned short* Vtb   = (unsigned short*)(ws + 64 * MB);
  unsigned short* attnO = (unsigned short*)(ws + 80 * MB);
  unsigned short* woT   = (unsigned short*)(ws + 96 * MB);
  unsigned short* qkvT  = (unsigned short*)(ws + 104 * MB);
  unsigned short* a1    = (unsigned short*)(ws + 32 * MB);
  unsigned short* h2    = (unsigned short*)(ws + 96 * MB);
  unsigned short* w1T   = (unsigned short*)(ws + 128 * MB);
  unsigned short* w2T   = (unsigned short*)(ws + 160 * MB);

  dim3 blk(256), blk5(512);
  ln_kernel<<<NTOK, blk, 0, stream>>>(x, ln1_scale, ln1_shift, h1);
  castT_kernel<<<dim3(32, 32), blk, 0, stream>>>(wq, qkvT, 2048, 2048);
  castT_kernel<<<dim3(32, 32), blk, 0, stream>>>(wk, qkvT + (size_t)2048 * 2048, 2048, 2048);
  castT_kernel<<<dim3(32, 32), blk, 0, stream>>>(wv, qkvT + (size_t)4096 * 2048, 2048, 2048);
  castT_kernel<<<dim3(32, 32), blk, 0, stream>>>(wo, woT, 2048, 2048);
  castT_kernel<<<dim3(32, 128), blk, 0, stream>>>(w1, w1T, 2048, 8192);
  castT_kernel<<<dim3(128, 32), blk, 0, stream>>>(w2, w2T, 8192, 2048);
  // QKV: BN=128, grid 48x16 = 768 blocks (3 exact CU-waves); xr=2,xc=4 -> rm=8, rn=12
  gemm256<128><<<dim3(48, 16), blk5, 0, stream>>>(
      h1, qkvT, nullptr, nullptr, nullptr, nullptr, 4096, 6144, 2048, 0, 1, Qb, Kb, Vtb,
      8, 12, 4);
  attn_mfma<<<dim3(TSEQ / 64, NHEAD, NBATCH), blk, 0, stream>>>(Qb, Kb, Vtb, attnO);
  // proj: BN=128, grid 16x16 = 256 blocks (1 exact wave); xr=4,xc=2 -> rm=4, rn=8
  gemm256<128><<<dim3(16, 16), blk5, 0, stream>>>(
      attnO, woT, x2, nullptr, nullptr, x, 4096, 2048, 2048, 0, 0, nullptr, nullptr, nullptr,
      4, 8, 2);
  ln_kernel<<<NTOK, blk, 0, stream>>>(x2, ln2_scale, ln2_shift, h2);
  // FFN1: BN=256, grid 32x16 = 512 blocks (2 exact waves); xr=2,xc=4 -> rm=8, rn=8
  gemm256<256><<<dim3(32, 16), blk5, 0, stream>>>(
      h2, w1T, nullptr, a1, b1, nullptr, 4096, 8192, 2048, 1, 0, nullptr, nullptr, nullptr,
      8, 8, 4);
  // FFN2: BN=128, grid 16x16 = 256 blocks; xr=4,xc=2 -> rm=4, rn=8
  gemm256<128><<<dim3(16, 16), blk5, 0, stream>>>(
      a1, w2T, (float*)d_out, nullptr, b2, x2, 4096, 2048, 8192, 0, 0, nullptr, nullptr, nullptr,
      4, 8, 2);
}

// Round 5
// 975.614 us; speedup vs baseline: 1.1626x; 1.1108x over previous
//
#include <hip/hip_runtime.h>
#include <math.h>

#define HDIM 2048
#define NTOK 4096
#define NHEAD 16
#define HEADD 128
#define TSEQ 2048
#define NBATCH 2

typedef float f32x4 __attribute__((ext_vector_type(4)));
typedef short bf16x8 __attribute__((ext_vector_type(8)));

__device__ __forceinline__ unsigned short f2bf(float f) {
  union { float f; unsigned u; } v; v.f = f;
  unsigned r = v.u + 0x7FFFu + ((v.u >> 16) & 1u);
  return (unsigned short)(r >> 16);
}

__device__ __forceinline__ float gelu_tanh_f(float x) {
  float z = 0.7978845608028654f * (x + 0.044715f * x * x * x);
  float e = __expf(2.f * z);
  float th = 1.f - 2.f / (e + 1.f);
  return 0.5f * x * (1.f + th);
}

#define GLL16(g, l) __builtin_amdgcn_global_load_lds( \
    (const __attribute__((address_space(1))) unsigned int*)(g), \
    (__attribute__((address_space(3))) unsigned int*)(l), 16, 0, 0)

// ---------------- LayerNorm: fp32 in, bf16 out. one block per token ----------------
__global__ __launch_bounds__(256) void ln_kernel(const float* __restrict__ in,
                                                 const float* __restrict__ scale,
                                                 const float* __restrict__ shift,
                                                 unsigned short* __restrict__ out) {
  int row = blockIdx.x;
  int t = threadIdx.x;
  const float4* r4 = (const float4*)(in + (size_t)row * HDIM);
  float4 v0 = r4[t];
  float4 v1 = r4[t + 256];
  float sum = v0.x + v0.y + v0.z + v0.w + v1.x + v1.y + v1.z + v1.w;
  float sq  = v0.x*v0.x + v0.y*v0.y + v0.z*v0.z + v0.w*v0.w +
              v1.x*v1.x + v1.y*v1.y + v1.z*v1.z + v1.w*v1.w;
  for (int o = 32; o > 0; o >>= 1) {
    sum += __shfl_down(sum, o);
    sq  += __shfl_down(sq, o);
  }
  __shared__ float red[8];
  __shared__ float stat[2];
  int lane = t & 63, w = t >> 6;
  if (lane == 0) { red[w] = sum; red[4 + w] = sq; }
  __syncthreads();
  if (t == 0) {
    float s = red[0] + red[1] + red[2] + red[3];
    float q = red[4] + red[5] + red[6] + red[7];
    float mean = s / HDIM;
    float var = q / HDIM - mean * mean;
    stat[0] = mean;
    stat[1] = rsqrtf(var + 1e-5f);
  }
  __syncthreads();
  float mean = stat[0], rstd = stat[1];
  const float4* sc4 = (const float4*)scale;
  const float4* sh4 = (const float4*)shift;
  float4 s0 = sc4[t], s1 = sc4[t + 256];
  float4 h0 = sh4[t], h1 = sh4[t + 256];
  ushort4 a, b;
  a.x = f2bf(s0.x * ((v0.x - mean) * rstd) + h0.x);
  a.y = f2bf(s0.y * ((v0.y - mean) * rstd) + h0.y);
  a.z = f2bf(s0.z * ((v0.z - mean) * rstd) + h0.z);
  a.w = f2bf(s0.w * ((v0.w - mean) * rstd) + h0.w);
  b.x = f2bf(s1.x * ((v1.x - mean) * rstd) + h1.x);
  b.y = f2bf(s1.y * ((v1.y - mean) * rstd) + h1.y);
  b.z = f2bf(s1.z * ((v1.z - mean) * rstd) + h1.z);
  b.w = f2bf(s1.w * ((v1.w - mean) * rstd) + h1.w);
  *(ushort4*)&out[(size_t)row * HDIM + t * 4] = a;
  *(ushort4*)&out[(size_t)row * HDIM + 1024 + t * 4] = b;
}

// ---------------- cast + transpose: W[K,N] fp32 -> Wt[N,K] bf16 ----------------
__global__ __launch_bounds__(256) void castT_kernel(const float* __restrict__ W,
                                                    unsigned short* __restrict__ Wt,
                                                    int K, int N) {
  __shared__ float T[64][65];
  int k0 = blockIdx.x * 64, n0 = blockIdx.y * 64;
  int c = threadIdx.x & 15, r = threadIdx.x >> 4;
#pragma unroll
  for (int p = 0; p < 4; p++) {
    int kr = r + p * 16;
    float4 v = *(const float4*)&W[(size_t)(k0 + kr) * N + n0 + c * 4];
    T[kr][c * 4 + 0] = v.x; T[kr][c * 4 + 1] = v.y;
    T[kr][c * 4 + 2] = v.z; T[kr][c * 4 + 3] = v.w;
  }
  __syncthreads();
#pragma unroll
  for (int p = 0; p < 4; p++) {
    int nr = r + p * 16;
    ushort4 o;
    o.x = f2bf(T[c * 4 + 0][nr]);
    o.y = f2bf(T[c * 4 + 1][nr]);
    o.z = f2bf(T[c * 4 + 2][nr]);
    o.w = f2bf(T[c * 4 + 3][nr]);
    *(ushort4*)&Wt[(size_t)(n0 + nr) * K + k0 + c * 4] = o;
  }
}

// ---------------- phase-pipelined 256-row MFMA GEMM: C[M,N] = A[M,K] @ Bt[N,K]^T -----
// BM=256, BK=64, 512 threads = 8 waves.
//   BN=256: waves 2M x 4N (wave tile 128x64), m201 quadrant 8-phase loop, 2 LDS bufs.
//   BN=128: waves 4M x 2N (wave tile 64x64), per-k-slice 2-phase/tile loop,
//     16 MFMA + 8 ds_read_b128 per phase (0.5 reads/MFMA, no B re-reads).
//     *** 3 LDS buffers (144KB) ***: tile t+2 is staged into buf((t+2)%3) during
//     tile t's phases; that buffer's last reader was tile t-1, already barrier-
//     separated.  (Round-3's 2-buffer version staged into the buffer being read ->
//     WAR race, absmax 5.6.  Staging may only target a region whose last read is
//     separated from the stage issue by a barrier.)
// Staging: global_load_lds w=16, linear LDS dest, inverse-swizzled global source,
//   ds_read chunk ^= row&7 (measured 0 bank conflicts; all staging rowbases == 0 mod 8).
// Counted vmcnt: 6 loads/tile/wave; vmcnt(6) once per tile (never 0 mid-loop).
// Fences carry NO memory clobbers (round-2 fix); ordering pinned with sched_barrier(0).
template<int BN>
__global__ __launch_bounds__(512, 2) void gemm256(const unsigned short* __restrict__ A,
                                                  const unsigned short* __restrict__ Bt,
                                                  float* __restrict__ Cf,
                                                  unsigned short* __restrict__ Cb,
                                                  const float* __restrict__ bias,
                                                  const float* __restrict__ resid,
                                                  int M, int N, int K, int act_gelu,
                                                  int qkv_mode,
                                                  unsigned short* __restrict__ Qo,
                                                  unsigned short* __restrict__ Ko,
                                                  unsigned short* __restrict__ Vto,
                                                  int rm, int rn, int xc) {
  constexpr int BSZ  = BN * 64;               // B tile elements per K-tile
  constexpr int AM   = (BN == 256) ? 8 : 4;   // acc m-frags per wave
  constexpr int AN   = 4;                     // acc n-frags per wave
  constexpr int NBUF = (BN == 256) ? 2 : 3;   // LDS buffers

  __shared__ unsigned short ldsA[NBUF * 16384];
  __shared__ unsigned short ldsB[NBUF * BSZ];

  const int tid = threadIdx.x;
  const int w = tid >> 6, lane = tid & 63;
  const int lm = lane & 15, qd = lane >> 4;
  const int l8 = lane >> 3, l7 = lane & 7;

  // XCD-aware tile swizzle (bijective: grid % 8 == 0 for all call sites)
  int flat = blockIdx.y * gridDim.x + blockIdx.x;
  int xcd = flat & 7, l = flat >> 3;
  int tn_l = l % rn, tm_l = l / rn;
  int tm = (xcd / xc) * rm + tm_l;
  int tn = (xcd % xc) * rn + tn_l;
  int m0 = tm * 256, n0 = tn * BN;

  // ---- staging addressing (linear LDS dest, inverse-swizzled global src) ----
  const int swz = ((l7 ^ (l8 & 7)) << 3);            // source k-chunk (elements)
  const int arb = (w >> 2) * 128 + (w & 3) * 16;     // A staging rowbase
  const unsigned short* pAs = A + (size_t)(m0 + arb + l8) * K + swz;
  unsigned short* lAs = ldsA + arb * 64;
  const int brb = (BN == 256) ? ((w >> 1) * 64 + (w & 1) * 16)
                              : ((w >> 1) * 32 + (w & 1) * 8);
  const unsigned short* pBs = Bt + (size_t)(n0 + brb + l8) * K + swz;
  unsigned short* lBs = ldsB + brb * 64;

  // ---- wave->output mapping ----
  const int wrA = (BN == 256) ? (w >> 2) * 128 : (w >> 1) * 64;  // wave row base
  const int wcB = (BN == 256) ? (w & 3) * 64  : (w & 1) * 64;    // wave col base

  // ---- fragment read addressing: chunk = (ks*4+qd) ^ (row&7), row&7 == lane&7 ----
  const int ca0 = ((qd ^ l7) << 3);                  // ks=0 (ks=1: ca0 ^ 32)
  const unsigned short* pAr = ldsA + (wrA + lm) * 64;
  const unsigned short* pBr = ldsB + (wcB + lm) * 64;

  f32x4 acc[AM][AN] = {};

// Fences: NO memory clobbers.  sched_barrier(0) pins order.
#define BARX() do { __builtin_amdgcn_sched_barrier(0); __builtin_amdgcn_s_barrier(); \
                    __builtin_amdgcn_sched_barrier(0); } while (0)
#define LGKM0() do { asm volatile("s_waitcnt lgkmcnt(0)"); \
                     __builtin_amdgcn_sched_barrier(0); } while (0)
#define VM6() do { asm volatile("s_waitcnt vmcnt(6)"); \
                   __builtin_amdgcn_sched_barrier(0); } while (0)
#define VM_0() do { asm volatile("s_waitcnt vmcnt(0)"); \
                    __builtin_amdgcn_sched_barrier(0); } while (0)

#define STAGE_A(buf, qm, kt) do { \
    const unsigned short* _s = pAs + (size_t)(qm) * 64 * K + (size_t)(kt) * 64; \
    unsigned short* _d = lAs + (buf) * 16384 + (qm) * 4096; \
    GLL16(_s, _d); \
    GLL16(_s + (size_t)8 * K, _d + 512); \
  } while (0)

  if constexpr (BN == 256) {
    const int niter = K >> 7;   // 2 K-tiles (BK=64) per iteration
    bf16x8 a[2][4], b[2][2];

#define STAGE_B(buf, qn, kt) do { \
    const unsigned short* _s = pBs + (size_t)(qn) * 32 * K + (size_t)(kt) * 64; \
    unsigned short* _d = lBs + (buf) * BSZ + (qn) * 2048; \
    GLL16(_s, _d); \
    GLL16(_s + (size_t)8 * K, _d + 512); \
  } while (0)

#define LDA(buf, qm) do { \
    _Pragma("unroll") \
    for (int mi = 0; mi < 4; mi++) { \
      a[0][mi] = *(const bf16x8*)(pAr + (buf) * 16384 + (qm) * 4096 + mi * 1024 + ca0); \
      a[1][mi] = *(const bf16x8*)(pAr + (buf) * 16384 + (qm) * 4096 + mi * 1024 + (ca0 ^ 32)); \
    } \
  } while (0)

#define LDB(buf, qn) do { \
    _Pragma("unroll") \
    for (int ni = 0; ni < 2; ni++) { \
      b[0][ni] = *(const bf16x8*)(pBr + (buf) * BSZ + (qn) * 2048 + ni * 1024 + ca0); \
      b[1][ni] = *(const bf16x8*)(pBr + (buf) * BSZ + (qn) * 2048 + ni * 1024 + (ca0 ^ 32)); \
    } \
  } while (0)

#define MFMA_PH(qm, qn) do { \
    __builtin_amdgcn_s_setprio(1); \
    _Pragma("unroll") \
    for (int ks = 0; ks < 2; ks++) \
      _Pragma("unroll") \
      for (int mi = 0; mi < 4; mi++) \
        _Pragma("unroll") \
        for (int ni = 0; ni < 2; ni++) \
          acc[(qm) * 4 + mi][(qn) * 2 + ni] = __builtin_amdgcn_mfma_f32_16x16x32_bf16( \
              a[ks][mi], b[ks][ni], acc[(qm) * 4 + mi][(qn) * 2 + ni], 0, 0, 0); \
    __builtin_amdgcn_s_setprio(0); \
  } while (0)

    // prologue: tile0 all 4 halves; tile1 {Ah0,Bh1,Ah1} (Bh0 staged at phase 1)
    STAGE_A(0, 0, 0); STAGE_B(0, 1, 0); STAGE_A(0, 1, 0); STAGE_B(0, 0, 0);
    STAGE_A(1, 0, 1); STAGE_B(1, 1, 1); STAGE_A(1, 1, 1);
    VM6();
    BARX();

    for (int i = 0; i < niter; ++i) {
      const bool pf = (i + 1 < niter);
      const int te = 2 * i + 2, to = 2 * i + 3;
      // phase 1: even tile (buf0), quadrant (0,0)
      LDA(0, 0); LDB(0, 0);
      STAGE_B(1, 0, 2 * i + 1);
      BARX(); LGKM0();
      MFMA_PH(0, 0);
      BARX();
      // phase 2: (0,1)
      LDB(0, 1);
      if (pf) STAGE_A(0, 0, te);
      BARX(); LGKM0();
      MFMA_PH(0, 1);
      BARX();
      // phase 3: (1,1)
      LDA(0, 1);
      if (pf) STAGE_B(0, 1, te);
      BARX(); LGKM0();
      MFMA_PH(1, 1);
      BARX();
      // phase 4: (1,0) + counted vmcnt (next-odd tile fully landed)
      LDB(0, 0);
      if (pf) STAGE_A(0, 1, te);
      BARX(); LGKM0();
      MFMA_PH(1, 0);
      if (pf) VM6(); else VM_0();
      BARX();
      // phase 5: odd tile (buf1), (0,0)
      LDA(1, 0); LDB(1, 0);
      if (pf) STAGE_B(0, 0, te);
      BARX(); LGKM0();
      MFMA_PH(0, 0);
      BARX();
      // phase 6: (0,1)
      LDB(1, 1);
      if (pf) STAGE_A(1, 0, to);
      BARX(); LGKM0();
      MFMA_PH(0, 1);
      BARX();
      // phase 7: (1,1)
      LDA(1, 1);
      if (pf) STAGE_B(1, 1, to);
      BARX(); LGKM0();
      MFMA_PH(1, 1);
      BARX();
      // phase 8: (1,0) + counted vmcnt (next-even tile fully landed)
      LDB(1, 0);
      if (pf) STAGE_A(1, 1, to);
      BARX(); LGKM0();
      MFMA_PH(1, 0);
      if (pf) VM6();
      BARX();
    }
#undef STAGE_B
#undef LDA
#undef LDB
#undef MFMA_PH

  } else {
    // ---- BN=128: 4Mx2N waves, 2 phases per K-tile, 3-buffer rotation ----
    const int ntiles = K >> 6;
    bf16x8 a2[4], b2[4];

#define SB128(buf, kt) do { \
    const unsigned short* _s = pBs + (size_t)(kt) * 64; \
    unsigned short* _d = lBs + (buf) * BSZ; \
    GLL16(_s, _d); \
    GLL16(_s + (size_t)16 * K, _d + 1024); \
  } while (0)

#define LDA128(buf, ks) do { \
    _Pragma("unroll") \
    for (int mi = 0; mi < 4; mi++) \
      a2[mi] = *(const bf16x8*)(pAr + (buf) * 16384 + mi * 1024 + ((ks) ? (ca0 ^ 32) : ca0)); \
  } while (0)

#define LDB128(buf, ks) do { \
    _Pragma("unroll") \
    for (int ni = 0; ni < 4; ni++) \
      b2[ni] = *(const bf16x8*)(pBr + (buf) * BSZ + ni * 1024 + ((ks) ? (ca0 ^ 32) : ca0)); \
  } while (0)

#define MFMA16() do { \
    __builtin_amdgcn_s_setprio(1); \
    _Pragma("unroll") \
    for (int mi = 0; mi < 4; mi++) \
      _Pragma("unroll") \
      for (int ni = 0; ni < 4; ni++) \
        acc[mi][ni] = __builtin_amdgcn_mfma_f32_16x16x32_bf16( \
            a2[mi], b2[ni], acc[mi][ni], 0, 0, 0); \
    __builtin_amdgcn_s_setprio(0); \
  } while (0)

    // prologue: tiles 0,1 fully staged (6 loads each, per wave)
    STAGE_A(0, 0, 0); STAGE_A(0, 1, 0); SB128(0, 0);
    STAGE_A(1, 0, 1); STAGE_A(1, 1, 1); SB128(1, 1);
    VM6();     // tile0 landed; tile1's 6 in flight
    BARX();

    int buf = 0, bs = 2;   // bs = (buf + 2) % 3 : stage target for tile t+2
    for (int t = 0; t < ntiles; ++t) {
      const bool pf = (t + 2 < ntiles);
      // Pa: ks=0 of tile t; stage A(t+2) -> bs (bs's last reader = tile t-1, barrier-sep)
      LDA128(buf, 0); LDB128(buf, 0);
      if (pf) { STAGE_A(bs, 0, t + 2); STAGE_A(bs, 1, t + 2); }
      BARX(); LGKM0();
      MFMA16();
      BARX();
      // Pb: ks=1 of tile t; stage B(t+2) -> bs; then wait tile t+1 landed
      LDA128(buf, 1); LDB128(buf, 1);
      if (pf) SB128(bs, t + 2);
      BARX(); LGKM0();
      MFMA16();
      if (pf) VM6(); else if (t + 1 < ntiles) VM_0();
      BARX();
      buf = (buf == 2) ? 0 : buf + 1;
      bs  = (bs  == 2) ? 0 : bs  + 1;
    }
#undef SB128
#undef LDA128
#undef LDB128
#undef MFMA16
  }

#undef STAGE_A
#undef BARX
#undef LGKM0
#undef VM6
#undef VM_0

  if (qkv_mode) {
#pragma unroll
    for (int ni = 0; ni < AN; ni++) {
      int n = n0 + wcB + ni * 16 + lm;
      int region = n >> 11;  // 0=Q, 1=K, 2=V
      int h = (n & 2047) >> 7, d = n & 127;
#pragma unroll
      for (int mi = 0; mi < AM; mi++) {
        int mb = m0 + wrA + mi * 16 + qd * 4;
        int bb = mb >> 11, t0 = mb & 2047;
        if (region == 2) {
          ushort4 u;
          u.x = f2bf(acc[mi][ni][0]); u.y = f2bf(acc[mi][ni][1]);
          u.z = f2bf(acc[mi][ni][2]); u.w = f2bf(acc[mi][ni][3]);
          *(ushort4*)&Vto[(((size_t)(bb * NHEAD + h)) * HEADD + d) * TSEQ + t0] = u;
        } else {
          unsigned short* dst = (region == 0) ? Qo : Ko;
          size_t base2 = (((size_t)(bb * NHEAD + h)) * TSEQ + t0) * HEADD + d;
#pragma unroll
          for (int r = 0; r < 4; r++)
            dst[base2 + (size_t)r * HEADD] = f2bf(acc[mi][ni][r]);
        }
      }
    }
    return;
  }

#pragma unroll
  for (int ni = 0; ni < AN; ni++) {
    int n = n0 + wcB + ni * 16 + lm;
    float bv = bias ? bias[n] : 0.f;
#pragma unroll
    for (int mi = 0; mi < AM; mi++) {
#pragma unroll
      for (int r = 0; r < 4; r++) {
        int m = m0 + wrA + mi * 16 + qd * 4 + r;
        float v = acc[mi][ni][r] + bv;
        if (act_gelu) v = gelu_tanh_f(v);
        if (resid) v += resid[(size_t)m * N + n];
        if (Cb) Cb[(size_t)m * N + n] = f2bf(v);
        else Cf[(size_t)m * N + n] = v;
      }
    }
  }
}

// ---------------- MFMA flash attention: BQ=64, BK=64, D=128, bf16 in/out ----------------
__global__ __launch_bounds__(256, 4) void attn_mfma(const unsigned short* __restrict__ Qb,
                                                    const unsigned short* __restrict__ Kb,
                                                    const unsigned short* __restrict__ Vtb,
                                                    unsigned short* __restrict__ O) {
  __shared__ unsigned short ldsK[64 * 128];
  __shared__ unsigned short ldsV[128 * 64];
  __shared__ unsigned short ldsP[64 * 64];

  int tid = threadIdx.x;
  int w = tid >> 6, lane = tid & 63;
  int lm = lane & 15, qd = lane >> 4;
  int qt = blockIdx.x, hh = blockIdx.y, bb = blockIdx.z;
  int q0 = qt * 64;
  size_t hbase = (size_t)(bb * NHEAD + hh) * (size_t)(TSEQ * HEADD);
  const unsigned short* Qh = Qb + hbase;
  const unsigned short* Kh = Kb + hbase;
  const unsigned short* Vh = Vtb + hbase;

  bf16x8 qf[4];
  {
    const unsigned short* qp = Qh + (size_t)(q0 + w * 16 + lm) * HEADD + qd * 8;
#pragma unroll
    for (int kc = 0; kc < 4; kc++) qf[kc] = *(const bf16x8*)(qp + kc * 32);
  }

  int koff[4], voff[4], ldst[4];
#pragma unroll
  for (int it = 0; it < 4; it++) {
    int ci = it * 256 + w * 64 + lane;
    int key = ci >> 4, pos = ci & 15;
    koff[it] = key * HEADD + ((pos ^ (key & 15)) << 3);
    int d = ci >> 3, pv = ci & 7;
    voff[it] = d * TSEQ + ((pv ^ (d & 7)) << 3);
    ldst[it] = (it * 256 + w * 64) * 8;
  }

  f32x4 oacc[8] = {};
  float mrow[4], lrow[4];
#pragma unroll
  for (int r = 0; r < 4; r++) { mrow[r] = -3.0e38f; lrow[r] = 0.f; }
  const float scl = 0.08838834764831845f;

  for (int kt = 0; kt <= qt; kt++) {
    int k0 = kt * 64;
    __syncthreads();
#pragma unroll
    for (int it = 0; it < 4; it++) {
      GLL16(Kh + (size_t)k0 * HEADD + koff[it], ldsK + ldst[it]);
      GLL16(Vh + k0 + voff[it], ldsV + ldst[it]);
    }
    __syncthreads();

    f32x4 sacc[4] = {};
#pragma unroll
    for (int kb = 0; kb < 4; kb++) {
#pragma unroll
      for (int kc = 0; kc < 4; kc++) {
        bf16x8 kf = *(const bf16x8*)(ldsK + (kb * 16 + lm) * HEADD + (((kc * 4 + qd) ^ lm) << 3));
        sacc[kb] = __builtin_amdgcn_mfma_f32_16x16x32_bf16(qf[kc], kf, sacc[kb], 0, 0, 0);
      }
    }

    float sv[4][4];
    int qrow_g = q0 + w * 16 + qd * 4;
    bool diag = (kt == qt);
#pragma unroll
    for (int kb = 0; kb < 4; kb++) {
      int key_g = k0 + kb * 16 + lm;
#pragma unroll
      for (int r = 0; r < 4; r++) {
        float x = sacc[kb][r] * scl;
        sv[kb][r] = (diag && key_g > qrow_g + r) ? -3.0e38f : x;
      }
    }
    float mloc[4];
#pragma unroll
    for (int r = 0; r < 4; r++)
      mloc[r] = fmaxf(fmaxf(sv[0][r], sv[1][r]), fmaxf(sv[2][r], sv[3][r]));
#pragma unroll
    for (int dm = 1; dm < 16; dm <<= 1)
#pragma unroll
      for (int r = 0; r < 4; r++) mloc[r] = fmaxf(mloc[r], __shfl_xor(mloc[r], dm));
    float al[4], lloc[4];
#pragma unroll
    for (int r = 0; r < 4; r++) {
      float mnew = fmaxf(mrow[r], mloc[r]);
      al[r] = __expf(mrow[r] - mnew);
      mrow[r] = mnew;
      lloc[r] = 0.f;
    }
#pragma unroll
    for (int kb = 0; kb < 4; kb++) {
#pragma unroll
      for (int r = 0; r < 4; r++) {
        float p = __expf(sv[kb][r] - mrow[r]);
        lloc[r] += p;
        int row = w * 16 + qd * 4 + r;
        int chunk = (kb * 2 + (lm >> 3)) ^ (row & 7);
        ldsP[row * 64 + chunk * 8 + (lm & 7)] = f2bf(p);
      }
    }
#pragma unroll
    for (int dm = 1; dm < 16; dm <<= 1)
#pragma unroll
      for (int r = 0; r < 4; r++) lloc[r] += __shfl_xor(lloc[r], dm);
#pragma unroll
    for (int r = 0; r < 4; r++) lrow[r] = lrow[r] * al[r] + lloc[r];
#pragma unroll
    for (int dt = 0; dt < 8; dt++)
#pragma unroll
      for (int r = 0; r < 4; r++) oacc[dt][r] *= al[r];

    bf16x8 pf[2];
#pragma unroll
    for (int kc2 = 0; kc2 < 2; kc2++)
      pf[kc2] = *(const bf16x8*)(ldsP + (w * 16 + lm) * 64 + (((kc2 * 4 + qd) ^ (lm & 7)) << 3));
#pragma unroll
    for (int dt = 0; dt < 8; dt++) {
#pragma unroll
      for (int kc2 = 0; kc2 < 2; kc2++) {
        bf16x8 vf = *(const bf16x8*)(ldsV + (dt * 16 + lm) * 64 + (((kc2 * 4 + qd) ^ (lm & 7)) << 3));
        oacc[dt] = __builtin_amdgcn_mfma_f32_16x16x32_bf16(pf[kc2], vf, oacc[dt], 0, 0, 0);
      }
    }
  }

  float inv[4];
#pragma unroll
  for (int r = 0; r < 4; r++) inv[r] = 1.f / lrow[r];
#pragma unroll
  for (int dt = 0; dt < 8; dt++) {
#pragma unroll
    for (int r = 0; r < 4; r++) {
      int t = q0 + w * 16 + qd * 4 + r;
      size_t idx = ((size_t)(bb * TSEQ + t)) * HDIM + hh * HEADD + dt * 16 + lm;
      O[idx] = f2bf(oacc[dt][r] * inv[r]);
    }
  }
}

// ---------------- launch ----------------
extern "C" void kernel_launch(void* const* d_in, const int* in_sizes, int n_in,
                              void* d_out, int out_size, void* d_ws, size_t ws_size,
                              hipStream_t stream) {
  const float* x         = (const float*)d_in[0];
  const float* wq        = (const float*)d_in[1];
  const float* wk        = (const float*)d_in[2];
  const float* wv        = (const float*)d_in[3];
  const float* wo        = (const float*)d_in[4];
  const float* ln1_scale = (const float*)d_in[5];
  const float* ln1_shift = (const float*)d_in[6];
  const float* ln2_scale = (const float*)d_in[7];
  const float* ln2_shift = (const float*)d_in[8];
  const float* w1        = (const float*)d_in[9];
  const float* b1        = (const float*)d_in[10];
  const float* w2        = (const float*)d_in[11];
  const float* b2        = (const float*)d_in[12];

  char* ws = (char*)d_ws;
  const size_t MB = 1ull << 20;
  unsigned short* h1    = (unsigned short*)(ws);
  float*          x2    = (float*)(ws);
  unsigned short* Qb    = (unsigned short*)(ws + 32 * MB);
  unsigned short* Kb    = (unsigned short*)(ws + 48 * MB);
  unsigned short* Vtb   = (unsigned short*)(ws + 64 * MB);
  unsigned short* attnO = (unsigned short*)(ws + 80 * MB);
  unsigned short* woT   = (unsigned short*)(ws + 96 * MB);
  unsigned short* qkvT  = (unsigned short*)(ws + 104 * MB);
  unsigned short* a1    = (unsigned short*)(ws + 32 * MB);
  unsigned short* h2    = (unsigned short*)(ws + 96 * MB);
  unsigned short* w1T   = (unsigned short*)(ws + 128 * MB);
  unsigned short* w2T   = (unsigned short*)(ws + 160 * MB);

  dim3 blk(256), blk5(512);
  ln_kernel<<<NTOK, blk, 0, stream>>>(x, ln1_scale, ln1_shift, h1);
  castT_kernel<<<dim3(32, 32), blk, 0, stream>>>(wq, qkvT, 2048, 2048);
  castT_kernel<<<dim3(32, 32), blk, 0, stream>>>(wk, qkvT + (size_t)2048 * 2048, 2048, 2048);
  castT_kernel<<<dim3(32, 32), blk, 0, stream>>>(wv, qkvT + (size_t)4096 * 2048, 2048, 2048);
  castT_kernel<<<dim3(32, 32), blk, 0, stream>>>(wo, woT, 2048, 2048);
  castT_kernel<<<dim3(32, 128), blk, 0, stream>>>(w1, w1T, 2048, 8192);
  castT_kernel<<<dim3(128, 32), blk, 0, stream>>>(w2, w2T, 8192, 2048);
  // QKV: BN=128, grid 48x16 = 768 blocks (3 exact CU-waves); xr=2,xc=4 -> rm=8, rn=12
  gemm256<128><<<dim3(48, 16), blk5, 0, stream>>>(
      h1, qkvT, nullptr, nullptr, nullptr, nullptr, 4096, 6144, 2048, 0, 1, Qb, Kb, Vtb,
      8, 12, 4);
  attn_mfma<<<dim3(TSEQ / 64, NHEAD, NBATCH), blk, 0, stream>>>(Qb, Kb, Vtb, attnO);
  // proj: BN=128, grid 16x16 = 256 blocks (1 exact wave); xr=4,xc=2 -> rm=4, rn=8
  gemm256<128><<<dim3(16, 16), blk5, 0, stream>>>(
      attnO, woT, x2, nullptr, nullptr, x, 4096, 2048, 2048, 0, 0, nullptr, nullptr, nullptr,
      4, 8, 2);
  ln_kernel<<<NTOK, blk, 0, stream>>>(x2, ln2_scale, ln2_shift, h2);
  // FFN1: BN=256, grid 32x16 = 512 blocks (2 exact waves); xr=2,xc=4 -> rm=8, rn=8
  gemm256<256><<<dim3(32, 16), blk5, 0, stream>>>(
      h2, w1T, nullptr, a1, b1, nullptr, 4096, 8192, 2048, 1, 0, nullptr, nullptr, nullptr,
      8, 8, 4);
  // FFN2: BN=128, grid 16x16 = 256 blocks; xr=4,xc=2 -> rm=4, rn=8
  gemm256<128><<<dim3(16, 16), blk5, 0, stream>>>(
      a1, w2T, (float*)d_out, nullptr, b2, x2, 4096, 2048, 8192, 0, 0, nullptr, nullptr, nullptr,
      4, 8, 2);
}